// Round 1
// baseline (286.873 us; speedup 1.0000x reference)
//
#include <hip/hip_runtime.h>
#include <math.h>

#define NCLS 80
#define NA 5
#define NH 32
#define NW 32
#define TBX 50            // MAX_BOXES
#define CH (5 + NCLS)     // 85 channels per anchor

__device__ __forceinline__ float sigm(float z) { return 1.0f / (1.0f + expf(-z)); }

// matches reference: -(t*clip(log p,-100) + (1-t)*clip(log1p(-p),-100))
__device__ __forceinline__ float bce(float p, float t) {
    float lp  = fmaxf(logf(p), -100.0f);
    float l1p = fmaxf(log1pf(-p), -100.0f);
    return -(t * lp + (1.0f - t) * l1p);
}

__global__ void zero_kernel(float* o) { o[0] = 0.0f; }

__global__ __launch_bounds__(256) void yolo_loss_kernel(
    const float* __restrict__ outp, const float* __restrict__ target,
    float* __restrict__ loss, float inv_nB)
{
    const int blk = blockIdx.x;      // b*NA + A
    const int b   = blk / NA;
    const int A   = blk - b * NA;
    const int tid = threadIdx.x;

    __shared__ float s_x[TBX];
    __shared__ int   s_gi[TBX], s_gj[TBX], s_cls[TBX];
    __shared__ float s_tx[TBX], s_ty[TBX], s_tw[TBX], s_th[TBX];
    __shared__ unsigned char s_valid[TBX], s_match[TBX], s_clear[TBX];

    // ---- phase 1: per-box metadata (threads 0..49) ----
    if (tid < TBX) {
        const float* tg = target + (size_t)b * TBX * 5 + tid * 5;
        float clsf = tg[0];
        float xx = tg[1], yy = tg[2], ww = tg[3], hh = tg[4];
        s_x[tid] = xx;
        float gx = xx * NW, gy = yy * NH, gw = ww * NW, gh = hh * NH;
        int gi = (int)gx; gi = min(max(gi, 0), NW - 1);   // trunc-toward-0 == astype(int32)
        int gj = (int)gy; gj = min(max(gj, 0), NH - 1);
        // scaled anchors (exact: /32 is an exponent shift)
        const float AW[NA] = {1.3125f, 3.1875f, 5.03125f, 9.46875f, 11.21875f};
        const float AH[NA] = {1.71875f, 4.0f,   8.09375f, 4.84375f, 10.0f};
        int best = 0; float bi = -1.0f, bw = 0.f, bh = 0.f, iouA = 0.f;
        #pragma unroll
        for (int a = 0; a < NA; ++a) {
            float aw = AW[a], ah = AH[a];
            float inter = fmaxf(fminf(gw, aw) + 1.0f, 0.0f) * fmaxf(fminf(gh, ah) + 1.0f, 0.0f);
            float iou = inter / ((gw + 1.0f) * (gh + 1.0f) + (aw + 1.0f) * (ah + 1.0f) - inter + 1e-16f);
            if (iou > bi) { bi = iou; best = a; bw = aw; bh = ah; }   // first max wins (strict >)
            if (a == A) iouA = iou;
        }
        s_gi[tid] = gi; s_gj[tid] = gj;
        s_match[tid] = (best == A) ? 1 : 0;
        s_tx[tid] = gx - (float)gi;
        s_ty[tid] = gy - (float)gj;
        s_tw[tid] = logf(fmaxf(gw, 1e-8f) / bw);
        s_th[tid] = logf(fmaxf(gh, 1e-8f) / bh);
        int cls = (int)clsf; cls = min(max(cls, 0), NCLS - 1);
        s_cls[tid] = cls;
        s_clear[tid] = ((iouA > 0.6f) || (best == A)) ? 1 : 0;  // valid ANDed in phase 2
    }
    __syncthreads();
    // ---- phase 2: validity = cumprod(x != 0) ----
    if (tid < TBX) {
        unsigned char v = 1;
        for (int s = 0; s <= tid; ++s) v &= (s_x[s] != 0.0f) ? 1 : 0;
        s_valid[tid] = v;
        s_clear[tid] = s_clear[tid] & v;
    }
    __syncthreads();

    // ---- phase 3: per-pixel loss, reading only contributing channels ----
    const float* base = outp + ((size_t)b * (NA * CH) + (size_t)A * CH) * (NH * NW);
    float lsum = 0.0f;

    #pragma unroll
    for (int k = 0; k < 4; ++k) {
        int p = tid + k * 256;         // 0..1023
        int i = p & (NW - 1);
        int j = p >> 5;
        float obj = 0.f, tx = 0.f, ty = 0.f, tw = 0.f, th = 0.f;
        unsigned cm0 = 0, cm1 = 0, cm2 = 0;   // 80-bit class mask (tcls is .max union)
        unsigned char clear = 0;
        for (int t = 0; t < TBX; ++t) {       // ascending: .set last-write-wins
            if (s_gi[t] == i && s_gj[t] == j) {
                clear |= s_clear[t];
                if (s_match[t]) {
                    unsigned char v = s_valid[t];
                    // .set scatters even for invalid boxes (value 0)
                    tx = v ? s_tx[t] : 0.f;
                    ty = v ? s_ty[t] : 0.f;
                    tw = v ? s_tw[t] : 0.f;
                    th = v ? s_th[t] : 0.f;
                    if (v) {
                        obj = 1.f;
                        int c = s_cls[t];
                        if (c < 32)      cm0 |= 1u << c;
                        else if (c < 64) cm1 |= 1u << (c - 32);
                        else             cm2 |= 1u << (c - 64);
                    }
                }
            }
        }
        if (obj != 0.f) {
            // full 85-channel cell (rare: ~10 per block)
            float o0 = base[0 * 1024 + p];
            float o1 = base[1 * 1024 + p];
            float o2 = base[2 * 1024 + p];
            float o3 = base[3 * 1024 + p];
            float o4 = base[4 * 1024 + p];
            lsum += bce(sigm(o0), tx);
            lsum += bce(sigm(o1), ty);
            float dw = o2 - tw, dh = o3 - th;
            lsum += dw * dw + dh * dh;
            lsum += -fmaxf(logf(sigm(o4)), -100.0f);          // bce(conf, 1)
            for (int c = 0; c < NCLS; ++c) {
                float oc = base[(5 + c) * 1024 + p];
                unsigned bit = (c < 32) ? ((cm0 >> c) & 1u)
                             : (c < 64) ? ((cm1 >> (c - 32)) & 1u)
                                        : ((cm2 >> (c - 64)) & 1u);
                lsum += bce(sigm(oc), bit ? 1.0f : 0.0f);
            }
            // obj==1 ⇒ clear==1 ⇒ noobj==0: no noobj term here
        } else if (!clear) {
            // noobj cell: only the conf channel contributes
            float o4 = base[4 * 1024 + p];
            lsum += -0.5f * fmaxf(log1pf(-sigm(o4)), -100.0f);  // 0.5*bce(conf, 0)
        }
    }

    // ---- reduce: wave64 shuffle + LDS across 4 waves ----
    #pragma unroll
    for (int off = 32; off > 0; off >>= 1)
        lsum += __shfl_down(lsum, off, 64);
    __shared__ float s_part[4];
    if ((tid & 63) == 0) s_part[tid >> 6] = lsum;
    __syncthreads();
    if (tid == 0) {
        float s = (s_part[0] + s_part[1] + s_part[2] + s_part[3]) * inv_nB;
        atomicAdd(loss, s);
    }
}

extern "C" void kernel_launch(void* const* d_in, const int* in_sizes, int n_in,
                              void* d_out, int out_size, void* d_ws, size_t ws_size,
                              hipStream_t stream) {
    const float* outp   = (const float*)d_in[0];
    const float* target = (const float*)d_in[1];
    float* loss = (float*)d_out;
    int nB = in_sizes[1] / (TBX * 5);   // 64
    zero_kernel<<<1, 1, 0, stream>>>(loss);
    yolo_loss_kernel<<<nB * NA, 256, 0, stream>>>(outp, target, loss, 1.0f / (float)nB);
}

// Round 2
// 37.917 us; speedup vs baseline: 7.5659x; 7.5659x over previous
//
#include <hip/hip_runtime.h>
#include <math.h>

#define NCLS 80
#define NA 5
#define NH 32
#define NW 32
#define TBX 50            // MAX_BOXES
#define CH (5 + NCLS)     // 85 channels per anchor
#define QPIX 256          // pixels per block (quarter of 32x32)

__device__ __forceinline__ float sigm(float z) { return 1.0f / (1.0f + expf(-z)); }

// matches reference: -(t*clip(log p,-100) + (1-t)*clip(log1p(-p),-100))
__device__ __forceinline__ float bce(float p, float t) {
    float lp  = fmaxf(logf(p), -100.0f);
    float l1p = fmaxf(log1pf(-p), -100.0f);
    return -(t * lp + (1.0f - t) * l1p);
}

__global__ void zero_kernel(float* o) { o[0] = 0.0f; }

__global__ __launch_bounds__(256) void yolo_loss_kernel(
    const float* __restrict__ outp, const float* __restrict__ target,
    float* __restrict__ loss, float inv_nB)
{
    const int blk = blockIdx.x;        // ((b*NA)+A)*4 + q
    const int q   = blk & 3;
    const int bA  = blk >> 2;
    const int b   = bA / NA;
    const int A   = bA - b * NA;
    const int tid = threadIdx.x;

    __shared__ float s_x[TBX];
    __shared__ float s_tx[TBX], s_ty[TBX], s_tw[TBX], s_th[TBX];
    __shared__ int   s_cell[TBX], s_cls[TBX];
    __shared__ unsigned char s_match[TBX], s_clearb[TBX], s_valid[TBX];
    __shared__ int      winner[QPIX];          // last matched box idx per cell (-1 none)
    __shared__ unsigned clsm[QPIX][3];         // 80-bit class union per cell
    __shared__ unsigned clearbits[QPIX / 32];  // 8 words
    __shared__ unsigned objbits[QPIX / 32];
    __shared__ int   objlist[TBX];
    __shared__ int   nobj;
    __shared__ float s_part[4];

    // ---- init LDS grids ----
    winner[tid] = -1;
    clsm[tid][0] = 0; clsm[tid][1] = 0; clsm[tid][2] = 0;
    if (tid < QPIX / 32) { clearbits[tid] = 0; objbits[tid] = 0; }
    if (tid == 0) nobj = 0;

    // ---- phase 1: per-box metadata ----
    if (tid < TBX) {
        const float* tg = target + (size_t)b * TBX * 5 + tid * 5;
        float clsf = tg[0];
        float xx = tg[1], yy = tg[2], ww = tg[3], hh = tg[4];
        s_x[tid] = xx;
        float gx = xx * NW, gy = yy * NH, gw = ww * NW, gh = hh * NH;
        int gi = (int)gx; gi = min(max(gi, 0), NW - 1);  // trunc == astype(int32)
        int gj = (int)gy; gj = min(max(gj, 0), NH - 1);
        const float AW[NA] = {1.3125f, 3.1875f, 5.03125f, 9.46875f, 11.21875f};
        const float AH[NA] = {1.71875f, 4.0f,   8.09375f, 4.84375f, 10.0f};
        int best = 0; float bi = -1.0f, bw = 0.f, bh = 0.f, iouA = 0.f;
        #pragma unroll
        for (int a = 0; a < NA; ++a) {
            float aw = AW[a], ah = AH[a];
            float inter = fmaxf(fminf(gw, aw) + 1.0f, 0.0f) * fmaxf(fminf(gh, ah) + 1.0f, 0.0f);
            float iou = inter / ((gw + 1.0f) * (gh + 1.0f) + (aw + 1.0f) * (ah + 1.0f) - inter + 1e-16f);
            if (iou > bi) { bi = iou; best = a; bw = aw; bh = ah; }   // first max wins
            if (a == A) iouA = iou;
        }
        s_cell[tid]  = gj * NW + gi;
        s_match[tid] = (best == A) ? 1 : 0;
        s_tx[tid] = gx - (float)gi;
        s_ty[tid] = gy - (float)gj;
        s_tw[tid] = logf(fmaxf(gw, 1e-8f) / bw);
        s_th[tid] = logf(fmaxf(gh, 1e-8f) / bh);
        int cls = (int)clsf; cls = min(max(cls, 0), NCLS - 1);
        s_cls[tid] = cls;
        s_clearb[tid] = ((iouA > 0.6f) || (best == A)) ? 1 : 0;
    }
    __syncthreads();

    // ---- phase 2: validity = cumprod(x!=0), then scatter into LDS grids ----
    if (tid < TBX) {
        unsigned char v = 1;
        for (int s = 0; s <= tid; ++s) v &= (s_x[s] != 0.0f) ? 1 : 0;
        s_valid[tid] = v;
        int cell = s_cell[tid];
        if ((cell >> 8) == q) {                  // cell lies in this block's quarter
            int p = cell & (QPIX - 1);
            if (s_clearb[tid] & v) atomicOr(&clearbits[p >> 5], 1u << (p & 31));
            if (s_match[tid]) {
                atomicMax(&winner[p], tid);      // .set last-write-wins == max box idx
                if (v) {
                    atomicOr(&objbits[p >> 5], 1u << (p & 31));
                    int c = s_cls[tid];
                    atomicOr(&clsm[p][c >> 5], 1u << (c & 31));
                }
            }
        }
    }
    __syncthreads();

    // ---- phase 3: one pixel per thread ----
    const float* base = outp + ((size_t)b * (NA * CH) + (size_t)A * CH) * (NH * NW)
                        + (size_t)q * QPIX;       // base[c*1024 + p], p in [0,256)
    float lsum = 0.0f;

    const int p = tid;
    unsigned objb = (objbits[p >> 5] >> (p & 31)) & 1u;
    unsigned clrb = (clearbits[p >> 5] >> (p & 31)) & 1u;
    if (objb) {
        int slot = atomicAdd(&nobj, 1);
        objlist[slot] = p;
    } else if (!clrb) {
        // noobj cell: only the conf channel contributes (coalesced load)
        float o4 = base[4 * 1024 + p];
        lsum += -0.5f * fmaxf(log1pf(-sigm(o4)), -100.0f);  // 0.5*bce(conf,0)
    }
    __syncthreads();

    // ---- phase 4: cooperative obj-cell processing (85 channels in parallel) ----
    const int n = nobj;
    for (int e = 0; e < n; ++e) {
        int pc = objlist[e];
        if (tid < CH) {
            float oc = base[tid * 1024 + pc];
            int w = winner[pc];
            unsigned char wv = s_valid[w];       // invalid winner => targets are 0
            float contrib;
            if (tid == 0)      contrib = bce(sigm(oc), wv ? s_tx[w] : 0.0f);
            else if (tid == 1) contrib = bce(sigm(oc), wv ? s_ty[w] : 0.0f);
            else if (tid == 2) { float d = oc - (wv ? s_tw[w] : 0.0f); contrib = d * d; }
            else if (tid == 3) { float d = oc - (wv ? s_th[w] : 0.0f); contrib = d * d; }
            else if (tid == 4) contrib = -fmaxf(logf(sigm(oc)), -100.0f);  // bce(conf,1)
            else {
                int c = tid - 5;
                unsigned bit = (clsm[pc][c >> 5] >> (c & 31)) & 1u;
                contrib = bce(sigm(oc), bit ? 1.0f : 0.0f);
            }
            lsum += contrib;
        }
    }

    // ---- reduce: wave64 shuffle + LDS across 4 waves ----
    #pragma unroll
    for (int off = 32; off > 0; off >>= 1)
        lsum += __shfl_down(lsum, off, 64);
    if ((tid & 63) == 0) s_part[tid >> 6] = lsum;
    __syncthreads();
    if (tid == 0) {
        float s = (s_part[0] + s_part[1] + s_part[2] + s_part[3]) * inv_nB;
        atomicAdd(loss, s);
    }
}

extern "C" void kernel_launch(void* const* d_in, const int* in_sizes, int n_in,
                              void* d_out, int out_size, void* d_ws, size_t ws_size,
                              hipStream_t stream) {
    const float* outp   = (const float*)d_in[0];
    const float* target = (const float*)d_in[1];
    float* loss = (float*)d_out;
    int nB = in_sizes[1] / (TBX * 5);   // 64
    zero_kernel<<<1, 1, 0, stream>>>(loss);
    yolo_loss_kernel<<<nB * NA * 4, 256, 0, stream>>>(outp, target, loss, 1.0f / (float)nB);
}

// Round 3
// 32.144 us; speedup vs baseline: 8.9247x; 1.1796x over previous
//
#include <hip/hip_runtime.h>
#include <math.h>

#define NCLS 80
#define NA 5
#define NH 32
#define NW 32
#define TBX 50            // MAX_BOXES
#define CH (5 + NCLS)     // 85 channels per anchor
#define QPIX 256          // pixels per block (quarter of 32x32)

__device__ __forceinline__ float sigm(float z) { return 1.0f / (1.0f + expf(-z)); }

// matches reference: -(t*clip(log p,-100) + (1-t)*clip(log1p(-p),-100))
__device__ __forceinline__ float bce(float p, float t) {
    float lp  = fmaxf(logf(p), -100.0f);
    float l1p = fmaxf(log1pf(-p), -100.0f);
    return -(t * lp + (1.0f - t) * l1p);
}

__global__ __launch_bounds__(256) void yolo_loss_kernel(
    const float* __restrict__ outp, const float* __restrict__ target,
    float* __restrict__ partials)
{
    const int blk = blockIdx.x;        // ((b*NA)+A)*4 + q
    const int q   = blk & 3;
    const int bA  = blk >> 2;
    const int b   = bA / NA;
    const int A   = bA - b * NA;
    const int tid = threadIdx.x;

    __shared__ float s_x[TBX];
    __shared__ float s_tx[TBX], s_ty[TBX], s_tw[TBX], s_th[TBX];
    __shared__ int   s_cell[TBX], s_cls[TBX];
    __shared__ unsigned char s_match[TBX], s_clearb[TBX], s_valid[TBX];
    __shared__ int      winner[QPIX];          // last matched box idx per cell (-1 none)
    __shared__ unsigned clsm[QPIX][3];         // 80-bit class union per cell
    __shared__ unsigned clearbits[QPIX / 32];  // 8 words
    __shared__ unsigned objbits[QPIX / 32];
    __shared__ int   objlist[TBX];
    __shared__ int   nobj;
    __shared__ float s_part[4];

    // ---- init LDS grids ----
    winner[tid] = -1;
    clsm[tid][0] = 0; clsm[tid][1] = 0; clsm[tid][2] = 0;
    if (tid < QPIX / 32) { clearbits[tid] = 0; objbits[tid] = 0; }
    if (tid == 0) nobj = 0;

    // ---- phase 1: per-box metadata ----
    if (tid < TBX) {
        const float* tg = target + (size_t)b * TBX * 5 + tid * 5;
        float clsf = tg[0];
        float xx = tg[1], yy = tg[2], ww = tg[3], hh = tg[4];
        s_x[tid] = xx;
        float gx = xx * NW, gy = yy * NH, gw = ww * NW, gh = hh * NH;
        int gi = (int)gx; gi = min(max(gi, 0), NW - 1);  // trunc == astype(int32)
        int gj = (int)gy; gj = min(max(gj, 0), NH - 1);
        const float AW[NA] = {1.3125f, 3.1875f, 5.03125f, 9.46875f, 11.21875f};
        const float AH[NA] = {1.71875f, 4.0f,   8.09375f, 4.84375f, 10.0f};
        int best = 0; float bi = -1.0f, bw = 0.f, bh = 0.f, iouA = 0.f;
        #pragma unroll
        for (int a = 0; a < NA; ++a) {
            float aw = AW[a], ah = AH[a];
            float inter = fmaxf(fminf(gw, aw) + 1.0f, 0.0f) * fmaxf(fminf(gh, ah) + 1.0f, 0.0f);
            float iou = inter / ((gw + 1.0f) * (gh + 1.0f) + (aw + 1.0f) * (ah + 1.0f) - inter + 1e-16f);
            if (iou > bi) { bi = iou; best = a; bw = aw; bh = ah; }   // first max wins
            if (a == A) iouA = iou;
        }
        s_cell[tid]  = gj * NW + gi;
        s_match[tid] = (best == A) ? 1 : 0;
        s_tx[tid] = gx - (float)gi;
        s_ty[tid] = gy - (float)gj;
        s_tw[tid] = logf(fmaxf(gw, 1e-8f) / bw);
        s_th[tid] = logf(fmaxf(gh, 1e-8f) / bh);
        int cls = (int)clsf; cls = min(max(cls, 0), NCLS - 1);
        s_cls[tid] = cls;
        s_clearb[tid] = ((iouA > 0.6f) || (best == A)) ? 1 : 0;
    }
    __syncthreads();

    // ---- phase 2: validity = cumprod(x!=0), then scatter into LDS grids ----
    if (tid < TBX) {
        unsigned char v = 1;
        for (int s = 0; s <= tid; ++s) v &= (s_x[s] != 0.0f) ? 1 : 0;
        s_valid[tid] = v;
        int cell = s_cell[tid];
        if ((cell >> 8) == q) {                  // cell lies in this block's quarter
            int p = cell & (QPIX - 1);
            if (s_clearb[tid] & v) atomicOr(&clearbits[p >> 5], 1u << (p & 31));
            if (s_match[tid]) {
                atomicMax(&winner[p], tid);      // .set last-write-wins == max box idx
                if (v) {
                    atomicOr(&objbits[p >> 5], 1u << (p & 31));
                    int c = s_cls[tid];
                    atomicOr(&clsm[p][c >> 5], 1u << (c & 31));
                }
            }
        }
    }
    __syncthreads();

    // ---- phase 3: one pixel per thread ----
    const float* base = outp + ((size_t)b * (NA * CH) + (size_t)A * CH) * (NH * NW)
                        + (size_t)q * QPIX;       // base[c*1024 + p], p in [0,256)
    float lsum = 0.0f;

    const int p = tid;
    unsigned objb = (objbits[p >> 5] >> (p & 31)) & 1u;
    unsigned clrb = (clearbits[p >> 5] >> (p & 31)) & 1u;
    if (objb) {
        int slot = atomicAdd(&nobj, 1);
        objlist[slot] = p;
    } else if (!clrb) {
        // noobj cell: only the conf channel contributes (coalesced load)
        float o4 = base[4 * 1024 + p];
        lsum += -0.5f * fmaxf(log1pf(-sigm(o4)), -100.0f);  // 0.5*bce(conf,0)
    }
    __syncthreads();

    // ---- phase 4: cooperative obj-cell processing (85 channels in parallel) ----
    const int n = nobj;
    for (int e = 0; e < n; ++e) {
        int pc = objlist[e];
        if (tid < CH) {
            float oc = base[tid * 1024 + pc];
            int w = winner[pc];
            unsigned char wv = s_valid[w];       // invalid winner => targets are 0
            float contrib;
            if (tid == 0)      contrib = bce(sigm(oc), wv ? s_tx[w] : 0.0f);
            else if (tid == 1) contrib = bce(sigm(oc), wv ? s_ty[w] : 0.0f);
            else if (tid == 2) { float d = oc - (wv ? s_tw[w] : 0.0f); contrib = d * d; }
            else if (tid == 3) { float d = oc - (wv ? s_th[w] : 0.0f); contrib = d * d; }
            else if (tid == 4) contrib = -fmaxf(logf(sigm(oc)), -100.0f);  // bce(conf,1)
            else {
                int c = tid - 5;
                unsigned bit = (clsm[pc][c >> 5] >> (c & 31)) & 1u;
                contrib = bce(sigm(oc), bit ? 1.0f : 0.0f);
            }
            lsum += contrib;
        }
    }

    // ---- reduce: wave64 shuffle + LDS across 4 waves, store partial ----
    #pragma unroll
    for (int off = 32; off > 0; off >>= 1)
        lsum += __shfl_down(lsum, off, 64);
    if ((tid & 63) == 0) s_part[tid >> 6] = lsum;
    __syncthreads();
    if (tid == 0)
        partials[blk] = s_part[0] + s_part[1] + s_part[2] + s_part[3];
}

__global__ __launch_bounds__(256) void reduce_kernel(
    const float* __restrict__ partials, float* __restrict__ out,
    int n, float inv_nB)
{
    const int tid = threadIdx.x;
    float s = 0.0f;
    for (int i = tid; i < n; i += 256) s += partials[i];
    #pragma unroll
    for (int off = 32; off > 0; off >>= 1)
        s += __shfl_down(s, off, 64);
    __shared__ float sp[4];
    if ((tid & 63) == 0) sp[tid >> 6] = s;
    __syncthreads();
    if (tid == 0)
        out[0] = (sp[0] + sp[1] + sp[2] + sp[3]) * inv_nB;
}

extern "C" void kernel_launch(void* const* d_in, const int* in_sizes, int n_in,
                              void* d_out, int out_size, void* d_ws, size_t ws_size,
                              hipStream_t stream) {
    const float* outp   = (const float*)d_in[0];
    const float* target = (const float*)d_in[1];
    float* loss = (float*)d_out;
    float* partials = (float*)d_ws;     // nB*NA*4 floats, every slot written each call
    int nB = in_sizes[1] / (TBX * 5);   // 64
    int nblk = nB * NA * 4;
    yolo_loss_kernel<<<nblk, 256, 0, stream>>>(outp, target, partials);
    reduce_kernel<<<1, 256, 0, stream>>>(partials, loss, nblk, 1.0f / (float)nB);
}

// Round 4
// 19.458 us; speedup vs baseline: 14.7431x; 1.6519x over previous
//
#include <hip/hip_runtime.h>
#include <math.h>

#define NCLS 80
#define NA 5
#define NH 32
#define NW 32
#define TBX 50            // MAX_BOXES
#define CH (5 + NCLS)     // 85 channels per anchor
#define QPIX 256          // pixels per block (quarter of 32x32)

__device__ __forceinline__ float sigm(float z) { return 1.0f / (1.0f + expf(-z)); }

// matches reference: -(t*clip(log p,-100) + (1-t)*clip(log1p(-p),-100))
__device__ __forceinline__ float bce(float p, float t) {
    float lp  = fmaxf(logf(p), -100.0f);
    float l1p = fmaxf(log1pf(-p), -100.0f);
    return -(t * lp + (1.0f - t) * l1p);
}

__global__ __launch_bounds__(256) void yolo_loss_kernel(
    const float* __restrict__ outp, const float* __restrict__ target,
    float* __restrict__ partials)
{
    const int blk = blockIdx.x;        // ((b*NA)+A)*4 + q
    const int q   = blk & 3;
    const int bA  = blk >> 2;
    const int b   = bA / NA;
    const int A   = bA - b * NA;
    const int tid = threadIdx.x;

    // issue the conf-plane load FIRST: its HBM latency hides under all the
    // metadata/scatter work below.
    const float* base = outp + ((size_t)b * (NA * CH) + (size_t)A * CH) * (NH * NW)
                        + (size_t)q * QPIX;       // base[c*1024 + p], p in [0,256)
    const float conf = base[4 * 1024 + tid];

    __shared__ float s_tx[TBX], s_ty[TBX], s_tw[TBX], s_th[TBX];
    __shared__ unsigned char s_valid[TBX];
    __shared__ int      winner[QPIX];          // last matched box idx per cell (-1 none)
    __shared__ unsigned clsm[QPIX][3];         // 80-bit class union per cell
    __shared__ unsigned clearbits[QPIX / 32];  // 8 words
    __shared__ unsigned objbits[QPIX / 32];
    __shared__ int   objlist[TBX];
    __shared__ float s_part[4];

    // ---- init LDS grids ----
    winner[tid] = -1;
    clsm[tid][0] = 0; clsm[tid][1] = 0; clsm[tid][2] = 0;
    if (tid < QPIX / 32) { clearbits[tid] = 0; objbits[tid] = 0; }

    // ---- phase 1: per-box metadata, all in registers (wave 0 only) ----
    const bool active = tid < TBX;
    int  cell = 0, cls = 0;
    bool match = false, clearb = false, v = false;
    if (active) {
        const float* tg = target + (size_t)b * TBX * 5 + tid * 5;
        float clsf = tg[0];
        float xx = tg[1], yy = tg[2], ww = tg[3], hh = tg[4];
        float gx = xx * NW, gy = yy * NH, gw = ww * NW, gh = hh * NH;
        int gi = (int)gx; gi = min(max(gi, 0), NW - 1);  // trunc == astype(int32)
        int gj = (int)gy; gj = min(max(gj, 0), NH - 1);
        const float AW[NA] = {1.3125f, 3.1875f, 5.03125f, 9.46875f, 11.21875f};
        const float AH[NA] = {1.71875f, 4.0f,   8.09375f, 4.84375f, 10.0f};
        int best = 0; float bi = -1.0f, bw = 0.f, bh = 0.f, iouA = 0.f;
        #pragma unroll
        for (int a = 0; a < NA; ++a) {
            float aw = AW[a], ah = AH[a];
            float inter = fmaxf(fminf(gw, aw) + 1.0f, 0.0f) * fmaxf(fminf(gh, ah) + 1.0f, 0.0f);
            float iou = inter / ((gw + 1.0f) * (gh + 1.0f) + (aw + 1.0f) * (ah + 1.0f) - inter + 1e-16f);
            if (iou > bi) { bi = iou; best = a; bw = aw; bh = ah; }   // first max wins
            if (a == A) iouA = iou;
        }
        cell   = gj * NW + gi;
        match  = (best == A);
        clearb = (iouA > 0.6f) || match;
        cls = (int)clsf; cls = min(max(cls, 0), NCLS - 1);
        // validity = cumprod(x != 0) via one ballot (lanes 0..49 in wave 0)
        unsigned long long m = __ballot(xx != 0.0f);
        v = (((~m) & ((1ULL << (tid + 1)) - 1ULL)) == 0ULL);
        s_valid[tid] = v ? 1 : 0;
        s_tx[tid] = gx - (float)gi;
        s_ty[tid] = gy - (float)gj;
        s_tw[tid] = logf(fmaxf(gw, 1e-8f) / bw);
        s_th[tid] = logf(fmaxf(gh, 1e-8f) / bh);
    }
    __syncthreads();   // LDS-grid init visible

    // ---- phase 2: scatter into LDS grids (registers carried across sync) ----
    if (active && (cell >> 8) == q) {            // cell lies in this block's quarter
        int p = cell & (QPIX - 1);
        if (clearb && v) atomicOr(&clearbits[p >> 5], 1u << (p & 31));
        if (match) {
            atomicMax(&winner[p], tid);          // .set last-write-wins == max box idx
            if (v) {
                atomicOr(&objbits[p >> 5], 1u << (p & 31));
                atomicOr(&clsm[p][cls >> 5], 1u << (cls & 31));
            }
        }
    }
    __syncthreads();

    // ---- phase 3: one pixel per thread; deterministic popcount-rank objlist ----
    float lsum = 0.0f;
    const int p = tid;
    const unsigned ow = objbits[p >> 5];
    const unsigned objb = (ow >> (p & 31)) & 1u;
    const unsigned clrb = (clearbits[p >> 5] >> (p & 31)) & 1u;
    if (objb) {
        int rank = __popc(ow & ((1u << (p & 31)) - 1u));
        for (int k = 0; k < (p >> 5); ++k) rank += __popc(objbits[k]);
        objlist[rank] = p;
    } else if (!clrb) {
        // noobj cell: conf channel only (value already in register)
        lsum += -0.5f * fmaxf(log1pf(-sigm(conf)), -100.0f);  // 0.5*bce(conf,0)
    }
    int nobj = 0;
    #pragma unroll
    for (int k = 0; k < QPIX / 32; ++k) nobj += __popc(objbits[k]);
    __syncthreads();   // objlist visible

    // ---- phase 4: obj cells flattened into nobj*85 parallel work items ----
    const int total = nobj * CH;
    for (int idx = tid; idx < total; idx += 256) {
        int e = idx / CH;               // const-85 division -> magic mul
        int c = idx - e * CH;
        int pc = objlist[e];
        float oc = base[c * 1024 + pc];
        int w = winner[pc];
        bool wv = s_valid[w] != 0;      // invalid winner => targets are 0
        float contrib;
        if (c == 0)      contrib = bce(sigm(oc), wv ? s_tx[w] : 0.0f);
        else if (c == 1) contrib = bce(sigm(oc), wv ? s_ty[w] : 0.0f);
        else if (c == 2) { float d = oc - (wv ? s_tw[w] : 0.0f); contrib = d * d; }
        else if (c == 3) { float d = oc - (wv ? s_th[w] : 0.0f); contrib = d * d; }
        else if (c == 4) contrib = -fmaxf(logf(sigm(oc)), -100.0f);  // bce(conf,1)
        else {
            int cc = c - 5;
            unsigned bit = (clsm[pc][cc >> 5] >> (cc & 31)) & 1u;
            contrib = bce(sigm(oc), bit ? 1.0f : 0.0f);
        }
        lsum += contrib;
    }

    // ---- reduce: wave64 shuffle + LDS across 4 waves, store partial ----
    #pragma unroll
    for (int off = 32; off > 0; off >>= 1)
        lsum += __shfl_down(lsum, off, 64);
    if ((tid & 63) == 0) s_part[tid >> 6] = lsum;
    __syncthreads();
    if (tid == 0)
        partials[blk] = s_part[0] + s_part[1] + s_part[2] + s_part[3];
}

__global__ __launch_bounds__(256) void reduce_kernel(
    const float* __restrict__ partials, float* __restrict__ out,
    int n, float inv_nB)
{
    const int tid = threadIdx.x;
    float s = 0.0f;
    for (int i = tid; i < n; i += 256) s += partials[i];
    #pragma unroll
    for (int off = 32; off > 0; off >>= 1)
        s += __shfl_down(s, off, 64);
    __shared__ float sp[4];
    if ((tid & 63) == 0) sp[tid >> 6] = s;
    __syncthreads();
    if (tid == 0)
        out[0] = (sp[0] + sp[1] + sp[2] + sp[3]) * inv_nB;
}

extern "C" void kernel_launch(void* const* d_in, const int* in_sizes, int n_in,
                              void* d_out, int out_size, void* d_ws, size_t ws_size,
                              hipStream_t stream) {
    const float* outp   = (const float*)d_in[0];
    const float* target = (const float*)d_in[1];
    float* loss = (float*)d_out;
    float* partials = (float*)d_ws;     // nB*NA*4 floats, every slot written each call
    int nB = in_sizes[1] / (TBX * 5);   // 64
    int nblk = nB * NA * 4;
    yolo_loss_kernel<<<nblk, 256, 0, stream>>>(outp, target, partials);
    reduce_kernel<<<1, 256, 0, stream>>>(partials, loss, nblk, 1.0f / (float)nB);
}